// Round 9
// baseline (342.143 us; speedup 1.0000x reference)
//
#include <hip/hip_runtime.h>

#define N_NODES 50000
#define N_EDGES 800000
#define F_IN    512
#define F_HID   64
#define F_OUT   16

#define SCAN_B  1024
#define SCAN_NB ((N_NODES + SCAN_B - 1) / SCAN_B)   // 49

typedef short bf16x8 __attribute__((ext_vector_type(8)));
typedef float f32x4  __attribute__((ext_vector_type(4)));

__device__ __forceinline__ short bhi_of(float v) {
    return (short)(__float_as_uint(v) >> 16);
}
__device__ __forceinline__ short blo_of(float v) {
    float hif = __uint_as_float(__float_as_uint(v) & 0xffff0000u);
    return (short)(__float_as_uint(v - hif) >> 16);
}

// ---------------- degree histogram ----------------
__global__ void k_count(const int* __restrict__ dst, int* __restrict__ count) {
    int e = blockIdx.x * blockDim.x + threadIdx.x;
    if (e < N_EDGES) atomicAdd(&count[dst[e]], 1);
}

// ---------------- GEMM1: canonical LDS-staged MFMA, split-bf16 ----------------
// Block: 256 thr / 4 waves, 64 rows. Wave w = col-tile w (16 cols), B register-
// resident (full-K unroll). A staged coalesced -> pre-split bf16 frags in LDS.
__global__ __launch_bounds__(256) void k_gemm1(const float* __restrict__ x,
                                               const float* __restrict__ W1,
                                               float* __restrict__ h) {
    __shared__ short Ahi[4][2][64][8];   // [m-tile][kstep][lane][elem] 8 KB
    __shared__ short Alo[4][2][64][8];   // 8 KB
    const int lane = threadIdx.x & 63;
    const int w    = threadIdx.x >> 6;   // wave = col-tile
    const int m    = lane & 15, q = lane >> 4;
    const int row0 = blockIdx.x * 64;

    // ---- B preload: 16 ksteps x (hi,lo), this wave's 16 cols (128 VGPRs) ----
    bf16x8 Bh[16], Bl[16];
#pragma unroll
    for (int s = 0; s < 16; ++s)
#pragma unroll
        for (int j = 0; j < 8; ++j) {
            float wv = W1[(size_t)(s * 32 + q * 8 + j) * F_HID + w * 16 + m];
            Bh[s][j] = bhi_of(wv);
            Bl[s][j] = blo_of(wv);
        }

    f32x4 acc[4] = {f32x4{0,0,0,0}, f32x4{0,0,0,0}, f32x4{0,0,0,0}, f32x4{0,0,0,0}};

    // staging geometry: slot = it*256+t; r=slot>>3 (row), qs=slot&7 (8-float col seg)
    int srow[2], sqs[2];
    const float* gbase[2];
#pragma unroll
    for (int it = 0; it < 2; ++it) {
        int slot = it * 256 + threadIdx.x;
        int r = slot >> 3, qs = slot & 7;
        int row = row0 + r;
        if (row >= N_NODES) row = N_NODES - 1;   // clamp loads; stores guarded
        srow[it] = r;
        sqs[it]  = qs;
        gbase[it] = x + (size_t)row * F_IN + qs * 8;
    }

    f32x4 p0[2], p1[2];
    // prologue: load chunk 0
#pragma unroll
    for (int it = 0; it < 2; ++it) {
        p0[it] = *(const f32x4*)(gbase[it]);
        p1[it] = *(const f32x4*)(gbase[it] + 4);
    }
    // split + write chunk 0
#pragma unroll
    for (int it = 0; it < 2; ++it) {
        int r = srow[it], qs = sqs[it];
        int mt = r >> 4, mm = r & 15, s2 = qs >> 2, qq = qs & 3;
        bf16x8 hi, lo;
#pragma unroll
        for (int j = 0; j < 8; ++j) {
            float v = (j < 4) ? p0[it][j] : p1[it][j - 4];
            hi[j] = bhi_of(v);
            lo[j] = blo_of(v);
        }
        *(bf16x8*)&Ahi[mt][s2][mm + 16 * qq][0] = hi;
        *(bf16x8*)&Alo[mt][s2][mm + 16 * qq][0] = lo;
    }

#pragma unroll
    for (int c = 0; c < 8; ++c) {
        __syncthreads();   // LDS chunk c ready
        if (c < 7) {
#pragma unroll
            for (int it = 0; it < 2; ++it) {
                p0[it] = *(const f32x4*)(gbase[it] + (c + 1) * 64);
                p1[it] = *(const f32x4*)(gbase[it] + (c + 1) * 64 + 4);
            }
        }
#pragma unroll
        for (int s2 = 0; s2 < 2; ++s2) {
            const int sg = c * 2 + s2;
#pragma unroll
            for (int mt = 0; mt < 4; ++mt) {
                bf16x8 ah = *(const bf16x8*)&Ahi[mt][s2][lane][0];
                bf16x8 al = *(const bf16x8*)&Alo[mt][s2][lane][0];
                acc[mt] = __builtin_amdgcn_mfma_f32_16x16x32_bf16(ah, Bh[sg], acc[mt], 0, 0, 0);
                acc[mt] = __builtin_amdgcn_mfma_f32_16x16x32_bf16(al, Bh[sg], acc[mt], 0, 0, 0);
                acc[mt] = __builtin_amdgcn_mfma_f32_16x16x32_bf16(ah, Bl[sg], acc[mt], 0, 0, 0);
            }
        }
        __syncthreads();   // all reads of chunk c done
        if (c < 7) {
#pragma unroll
            for (int it = 0; it < 2; ++it) {
                int r = srow[it], qs = sqs[it];
                int mt = r >> 4, mm = r & 15, s2 = qs >> 2, qq = qs & 3;
                bf16x8 hi, lo;
#pragma unroll
                for (int j = 0; j < 8; ++j) {
                    float v = (j < 4) ? p0[it][j] : p1[it][j - 4];
                    hi[j] = bhi_of(v);
                    lo[j] = blo_of(v);
                }
                *(bf16x8*)&Ahi[mt][s2][mm + 16 * qq][0] = hi;
                *(bf16x8*)&Alo[mt][s2][mm + 16 * qq][0] = lo;
            }
        }
    }

    // epilogue: D row = q*4 + ri (within m-tile), col = w*16 + (lane&15)
#pragma unroll
    for (int mt = 0; mt < 4; ++mt)
#pragma unroll
        for (int ri = 0; ri < 4; ++ri) {
            int row = row0 + mt * 16 + q * 4 + ri;
            if (row < N_NODES)
                h[(size_t)row * F_HID + w * 16 + m] = acc[mt][ri];
        }
}

// ---------------- scanA: block-local exclusive scan + dinv --------------------
__global__ __launch_bounds__(SCAN_B) void k_scanA(const int* __restrict__ count,
                                                  int* __restrict__ offs,
                                                  int* __restrict__ bsum,
                                                  float* __restrict__ dinv) {
    __shared__ int s[SCAN_B];
    int t = threadIdx.x;
    int i = blockIdx.x * SCAN_B + t;
    int v = (i < N_NODES) ? count[i] : 0;
    s[t] = v;
    __syncthreads();
    for (int off = 1; off < SCAN_B; off <<= 1) {
        int u = (t >= off) ? s[t - off] : 0;
        __syncthreads();
        s[t] += u;
        __syncthreads();
    }
    if (i < N_NODES) {
        offs[i] = s[t] - v;
        dinv[i] = rsqrtf((float)(v + 1));
    }
    if (t == SCAN_B - 1) bsum[blockIdx.x] = s[t];
}

// ---------------- scanBC: per-block redundant reduce of block sums ------------
__global__ __launch_bounds__(SCAN_B) void k_scanBC(int* __restrict__ offs,
                                                   const int* __restrict__ bsum) {
    __shared__ int base;
    if (threadIdx.x < 64) {
        int v = ((int)threadIdx.x < (int)blockIdx.x) ? bsum[threadIdx.x] : 0;
        for (int d = 1; d < 64; d <<= 1) v += __shfl_xor(v, d);
        if (threadIdx.x == 0) base = v;
    }
    __syncthreads();
    int i = blockIdx.x * SCAN_B + threadIdx.x;
    if (i < N_NODES) offs[i] += base;
    if (i == 0) offs[N_NODES] = N_EDGES;
}

// ---------------- fill: atomicSub on degree array claims slots ----------------
__global__ void k_fill(const int* __restrict__ src, const int* __restrict__ dst,
                       const int* __restrict__ offs, int* __restrict__ count,
                       const float* __restrict__ dinv,
                       int* __restrict__ src_sorted, float* __restrict__ w_sorted) {
    int e = blockIdx.x * blockDim.x + threadIdx.x;
    if (e < N_EDGES) {
        int d = dst[e];
        int s = src[e];
        int pos = atomicSub(&count[d], 1) - 1;
        int slot = offs[d] + pos;
        src_sorted[slot] = s;
        w_sorted[slot] = dinv[s] * dinv[d];
    }
}

// ---------------- CSR aggregation F=64: unroll-8, 4 acc chains ----------------
__global__ __launch_bounds__(256) void k_agg64_csr(const int* __restrict__ offs,
                                                   const int* __restrict__ srcs,
                                                   const float* __restrict__ wgt,
                                                   const float* __restrict__ dinv,
                                                   const float* __restrict__ h,
                                                   const float* __restrict__ b1,
                                                   float* __restrict__ h1) {
    int node = blockIdx.x * 4 + (threadIdx.x >> 6);
    int j = threadIdx.x & 63;
    if (node >= N_NODES) return;
    float dn = dinv[node];
    float acc0 = h[(size_t)node * F_HID + j] * dn * dn;
    float acc1 = 0.0f, acc2 = 0.0f, acc3 = 0.0f;
    int k0 = offs[node], k1 = offs[node + 1];
    int k = k0;
    for (; k + 8 <= k1; k += 8) {
        int s0 = srcs[k],     s1 = srcs[k + 1], s2 = srcs[k + 2], s3 = srcs[k + 3];
        int s4 = srcs[k + 4], s5 = srcs[k + 5], s6 = srcs[k + 6], s7 = srcs[k + 7];
        float w0 = wgt[k],     w1 = wgt[k + 1], w2 = wgt[k + 2], w3 = wgt[k + 3];
        float w4 = wgt[k + 4], w5 = wgt[k + 5], w6 = wgt[k + 6], w7 = wgt[k + 7];
        float v0 = h[(size_t)s0 * F_HID + j];
        float v1 = h[(size_t)s1 * F_HID + j];
        float v2 = h[(size_t)s2 * F_HID + j];
        float v3 = h[(size_t)s3 * F_HID + j];
        float v4 = h[(size_t)s4 * F_HID + j];
        float v5 = h[(size_t)s5 * F_HID + j];
        float v6 = h[(size_t)s6 * F_HID + j];
        float v7 = h[(size_t)s7 * F_HID + j];
        acc0 = fmaf(v0, w0, acc0);
        acc1 = fmaf(v1, w1, acc1);
        acc2 = fmaf(v2, w2, acc2);
        acc3 = fmaf(v3, w3, acc3);
        acc0 = fmaf(v4, w4, acc0);
        acc1 = fmaf(v5, w5, acc1);
        acc2 = fmaf(v6, w6, acc2);
        acc3 = fmaf(v7, w7, acc3);
    }
    for (; k < k1; ++k)
        acc0 = fmaf(h[(size_t)srcs[k] * F_HID + j], wgt[k], acc0);
    h1[(size_t)node * F_HID + j] = fmaxf((acc0 + acc1) + (acc2 + acc3) + b1[j], 0.0f);
}

// ---------------- GEMM2: h1[N,64] @ W2[64,16] -> h2[N,16] ----------------
__global__ void k_gemm2(const float* __restrict__ h1, const float* __restrict__ W,
                        float* __restrict__ h2) {
    int t = blockIdx.x * blockDim.x + threadIdx.x;
    if (t < N_NODES * F_OUT) {
        int i = t >> 4, j = t & 15;
        float acc = 0.0f;
#pragma unroll
        for (int k = 0; k < F_HID; ++k)
            acc = fmaf(h1[(size_t)i * F_HID + k], W[k * F_OUT + j], acc);
        h2[t] = acc;
    }
}

// ---------------- CSR aggregation F=16: 4 groups x 16 feats, unroll-4 ---------
__global__ __launch_bounds__(256) void k_agg16_csr(const int* __restrict__ offs,
                                                   const int* __restrict__ srcs,
                                                   const float* __restrict__ wgt,
                                                   const float* __restrict__ dinv,
                                                   const float* __restrict__ h2,
                                                   const float* __restrict__ b2,
                                                   float* __restrict__ out) {
    int node = blockIdx.x * 4 + (threadIdx.x >> 6);
    int lane = threadIdx.x & 63;
    int eo = lane >> 4;
    int j  = lane & 15;
    if (node >= N_NODES) return;
    float dn = dinv[node];
    float acc0 = 0.0f, acc1 = 0.0f, acc2 = 0.0f, acc3 = 0.0f;
    int k0 = offs[node], k1 = offs[node + 1];
    int k = k0 + eo;
    for (; k + 12 < k1; k += 16) {
        int s0 = srcs[k], s1 = srcs[k + 4], s2 = srcs[k + 8], s3 = srcs[k + 12];
        float w0 = wgt[k], w1 = wgt[k + 4], w2 = wgt[k + 8], w3 = wgt[k + 12];
        float v0 = h2[(size_t)s0 * F_OUT + j];
        float v1 = h2[(size_t)s1 * F_OUT + j];
        float v2 = h2[(size_t)s2 * F_OUT + j];
        float v3 = h2[(size_t)s3 * F_OUT + j];
        acc0 = fmaf(v0, w0, acc0);
        acc1 = fmaf(v1, w1, acc1);
        acc2 = fmaf(v2, w2, acc2);
        acc3 = fmaf(v3, w3, acc3);
    }
    for (; k < k1; k += 4)
        acc0 = fmaf(h2[(size_t)srcs[k] * F_OUT + j], wgt[k], acc0);
    float acc = (acc0 + acc1) + (acc2 + acc3);
    acc += __shfl_xor(acc, 16);
    acc += __shfl_xor(acc, 32);
    if (eo == 0)
        out[(size_t)node * F_OUT + j] =
            acc + h2[(size_t)node * F_OUT + j] * dn * dn + b2[j];
}

extern "C" void kernel_launch(void* const* d_in, const int* in_sizes, int n_in,
                              void* d_out, int out_size, void* d_ws, size_t ws_size,
                              hipStream_t stream) {
    const float* x  = (const float*)d_in[0];
    const int*   ei = (const int*)d_in[1];
    const float* W1 = (const float*)d_in[2];
    const float* b1 = (const float*)d_in[3];
    const float* W2 = (const float*)d_in[4];
    const float* b2 = (const float*)d_in[5];
    float* out = (float*)d_out;

    const int* src = ei;
    const int* dst = ei + N_EDGES;

    int* wsi = (int*)d_ws;
    int* count      = wsi;                  // 50176 (consumed to 0 by k_fill)
    int* offs       = count + 50176;        // 50304
    int* bsum       = offs + 50304;         // 64
    int* src_sorted = bsum + 64;            // 800000
    float* w_sorted = (float*)(src_sorted + N_EDGES);    // 800000
    float* dinv = w_sorted + N_EDGES;                    // 50176
    float* h    = dinv + 50176;                          // N*64
    float* h1   = h + (size_t)N_NODES * F_HID;           // N*64
    float* h2   = h;                                     // alias: h dead after agg64

    (void)hipMemsetAsync(count, 0, N_NODES * sizeof(int), stream);

    k_count<<<(N_EDGES + 255) / 256, 256, 0, stream>>>(dst, count);
    k_gemm1<<<(N_NODES + 63) / 64, 256, 0, stream>>>(x, W1, h);

    k_scanA<<<SCAN_NB, SCAN_B, 0, stream>>>(count, offs, bsum, dinv);
    k_scanBC<<<SCAN_NB, SCAN_B, 0, stream>>>(offs, bsum);
    k_fill<<<(N_EDGES + 255) / 256, 256, 0, stream>>>(src, dst, offs, count, dinv,
                                                      src_sorted, w_sorted);

    k_agg64_csr<<<(N_NODES + 3) / 4, 256, 0, stream>>>(offs, src_sorted, w_sorted,
                                                       dinv, h, b1, h1);
    k_gemm2<<<(N_NODES * F_OUT + 255) / 256, 256, 0, stream>>>(h1, W2, h2);
    k_agg16_csr<<<(N_NODES + 3) / 4, 256, 0, stream>>>(offs, src_sorted, w_sorted,
                                                       dinv, h2, b2, out);
}

// Round 10
// 334.384 us; speedup vs baseline: 1.0232x; 1.0232x over previous
//
#include <hip/hip_runtime.h>

#define N_NODES 50000
#define N_EDGES 800000
#define F_IN    512
#define F_HID   64
#define F_OUT   16

#define SCAN_B  1024
#define SCAN_NB ((N_NODES + SCAN_B - 1) / SCAN_B)   // 49

typedef short bf16x8 __attribute__((ext_vector_type(8)));
typedef float f32x4  __attribute__((ext_vector_type(4)));

__device__ __forceinline__ short bhi_of(float v) {
    return (short)(__float_as_uint(v) >> 16);
}
__device__ __forceinline__ short blo_of(float v) {
    float hif = __uint_as_float(__float_as_uint(v) & 0xffff0000u);
    return (short)(__float_as_uint(v - hif) >> 16);
}

// ---------------- degree histogram ----------------
__global__ void k_count(const int* __restrict__ dst, int* __restrict__ count) {
    int e = blockIdx.x * blockDim.x + threadIdx.x;
    if (e < N_EDGES) atomicAdd(&count[dst[e]], 1);
}

// ---------------- GEMM1: canonical LDS-staged MFMA, split-bf16 ----------------
__global__ __launch_bounds__(256) void k_gemm1(const float* __restrict__ x,
                                               const float* __restrict__ W1,
                                               float* __restrict__ h) {
    __shared__ short Ahi[4][2][64][8];
    __shared__ short Alo[4][2][64][8];
    const int lane = threadIdx.x & 63;
    const int w    = threadIdx.x >> 6;
    const int m    = lane & 15, q = lane >> 4;
    const int row0 = blockIdx.x * 64;

    bf16x8 Bh[16], Bl[16];
#pragma unroll
    for (int s = 0; s < 16; ++s)
#pragma unroll
        for (int j = 0; j < 8; ++j) {
            float wv = W1[(size_t)(s * 32 + q * 8 + j) * F_HID + w * 16 + m];
            Bh[s][j] = bhi_of(wv);
            Bl[s][j] = blo_of(wv);
        }

    f32x4 acc[4] = {f32x4{0,0,0,0}, f32x4{0,0,0,0}, f32x4{0,0,0,0}, f32x4{0,0,0,0}};

    int srow[2], sqs[2];
    const float* gbase[2];
#pragma unroll
    for (int it = 0; it < 2; ++it) {
        int slot = it * 256 + threadIdx.x;
        int r = slot >> 3, qs = slot & 7;
        int row = row0 + r;
        if (row >= N_NODES) row = N_NODES - 1;
        srow[it] = r;
        sqs[it]  = qs;
        gbase[it] = x + (size_t)row * F_IN + qs * 8;
    }

    f32x4 p0[2], p1[2];
#pragma unroll
    for (int it = 0; it < 2; ++it) {
        p0[it] = *(const f32x4*)(gbase[it]);
        p1[it] = *(const f32x4*)(gbase[it] + 4);
    }
#pragma unroll
    for (int it = 0; it < 2; ++it) {
        int r = srow[it], qs = sqs[it];
        int mt = r >> 4, mm = r & 15, s2 = qs >> 2, qq = qs & 3;
        bf16x8 hi, lo;
#pragma unroll
        for (int j = 0; j < 8; ++j) {
            float v = (j < 4) ? p0[it][j] : p1[it][j - 4];
            hi[j] = bhi_of(v);
            lo[j] = blo_of(v);
        }
        *(bf16x8*)&Ahi[mt][s2][mm + 16 * qq][0] = hi;
        *(bf16x8*)&Alo[mt][s2][mm + 16 * qq][0] = lo;
    }

#pragma unroll
    for (int c = 0; c < 8; ++c) {
        __syncthreads();
        if (c < 7) {
#pragma unroll
            for (int it = 0; it < 2; ++it) {
                p0[it] = *(const f32x4*)(gbase[it] + (c + 1) * 64);
                p1[it] = *(const f32x4*)(gbase[it] + (c + 1) * 64 + 4);
            }
        }
#pragma unroll
        for (int s2 = 0; s2 < 2; ++s2) {
            const int sg = c * 2 + s2;
#pragma unroll
            for (int mt = 0; mt < 4; ++mt) {
                bf16x8 ah = *(const bf16x8*)&Ahi[mt][s2][lane][0];
                bf16x8 al = *(const bf16x8*)&Alo[mt][s2][lane][0];
                acc[mt] = __builtin_amdgcn_mfma_f32_16x16x32_bf16(ah, Bh[sg], acc[mt], 0, 0, 0);
                acc[mt] = __builtin_amdgcn_mfma_f32_16x16x32_bf16(al, Bh[sg], acc[mt], 0, 0, 0);
                acc[mt] = __builtin_amdgcn_mfma_f32_16x16x32_bf16(ah, Bl[sg], acc[mt], 0, 0, 0);
            }
        }
        __syncthreads();
        if (c < 7) {
#pragma unroll
            for (int it = 0; it < 2; ++it) {
                int r = srow[it], qs = sqs[it];
                int mt = r >> 4, mm = r & 15, s2 = qs >> 2, qq = qs & 3;
                bf16x8 hi, lo;
#pragma unroll
                for (int j = 0; j < 8; ++j) {
                    float v = (j < 4) ? p0[it][j] : p1[it][j - 4];
                    hi[j] = bhi_of(v);
                    lo[j] = blo_of(v);
                }
                *(bf16x8*)&Ahi[mt][s2][mm + 16 * qq][0] = hi;
                *(bf16x8*)&Alo[mt][s2][mm + 16 * qq][0] = lo;
            }
        }
    }

#pragma unroll
    for (int mt = 0; mt < 4; ++mt)
#pragma unroll
        for (int ri = 0; ri < 4; ++ri) {
            int row = row0 + mt * 16 + q * 4 + ri;
            if (row < N_NODES)
                h[(size_t)row * F_HID + w * 16 + m] = acc[mt][ri];
        }
}

// ---------------- scanA: block-local exclusive scan + dinv --------------------
__global__ __launch_bounds__(SCAN_B) void k_scanA(const int* __restrict__ count,
                                                  int* __restrict__ offs,
                                                  int* __restrict__ bsum,
                                                  float* __restrict__ dinv) {
    __shared__ int s[SCAN_B];
    int t = threadIdx.x;
    int i = blockIdx.x * SCAN_B + t;
    int v = (i < N_NODES) ? count[i] : 0;
    s[t] = v;
    __syncthreads();
    for (int off = 1; off < SCAN_B; off <<= 1) {
        int u = (t >= off) ? s[t - off] : 0;
        __syncthreads();
        s[t] += u;
        __syncthreads();
    }
    if (i < N_NODES) {
        offs[i] = s[t] - v;
        dinv[i] = rsqrtf((float)(v + 1));
    }
    if (t == SCAN_B - 1) bsum[blockIdx.x] = s[t];
}

// ---------------- scanBC: per-block redundant reduce of block sums ------------
__global__ __launch_bounds__(SCAN_B) void k_scanBC(int* __restrict__ offs,
                                                   const int* __restrict__ bsum) {
    __shared__ int base;
    if (threadIdx.x < 64) {
        int v = ((int)threadIdx.x < (int)blockIdx.x) ? bsum[threadIdx.x] : 0;
        for (int d = 1; d < 64; d <<= 1) v += __shfl_xor(v, d);
        if (threadIdx.x == 0) base = v;
    }
    __syncthreads();
    int i = blockIdx.x * SCAN_B + threadIdx.x;
    if (i < N_NODES) offs[i] += base;
    if (i == 0) offs[N_NODES] = N_EDGES;
}

// ---------------- fill: single 8B packed (src, weight) scattered write --------
__global__ void k_fill(const int* __restrict__ src, const int* __restrict__ dst,
                       const int* __restrict__ offs, int* __restrict__ count,
                       const float* __restrict__ dinv,
                       int2* __restrict__ sw_sorted) {
    int e = blockIdx.x * blockDim.x + threadIdx.x;
    if (e < N_EDGES) {
        int d = dst[e];
        int s = src[e];
        int pos = atomicSub(&count[d], 1) - 1;
        float w = dinv[s] * dinv[d];
        sw_sorted[offs[d] + pos] = make_int2(s, __float_as_int(w));
    }
}

// ---------------- CSR aggregation F=64: unroll-8, 4 acc chains ----------------
__global__ __launch_bounds__(256) void k_agg64_csr(const int* __restrict__ offs,
                                                   const int2* __restrict__ sw,
                                                   const float* __restrict__ dinv,
                                                   const float* __restrict__ h,
                                                   const float* __restrict__ b1,
                                                   float* __restrict__ h1) {
    int node = blockIdx.x * 4 + (threadIdx.x >> 6);
    int j = threadIdx.x & 63;
    if (node >= N_NODES) return;
    float dn = dinv[node];
    float acc0 = h[(size_t)node * F_HID + j] * dn * dn;
    float acc1 = 0.0f, acc2 = 0.0f, acc3 = 0.0f;
    int k0 = offs[node], k1 = offs[node + 1];
    int k = k0;
    for (; k + 8 <= k1; k += 8) {
        int2 e0 = sw[k],     e1 = sw[k + 1], e2 = sw[k + 2], e3 = sw[k + 3];
        int2 e4 = sw[k + 4], e5 = sw[k + 5], e6 = sw[k + 6], e7 = sw[k + 7];
        float v0 = h[(size_t)e0.x * F_HID + j];
        float v1 = h[(size_t)e1.x * F_HID + j];
        float v2 = h[(size_t)e2.x * F_HID + j];
        float v3 = h[(size_t)e3.x * F_HID + j];
        float v4 = h[(size_t)e4.x * F_HID + j];
        float v5 = h[(size_t)e5.x * F_HID + j];
        float v6 = h[(size_t)e6.x * F_HID + j];
        float v7 = h[(size_t)e7.x * F_HID + j];
        acc0 = fmaf(v0, __int_as_float(e0.y), acc0);
        acc1 = fmaf(v1, __int_as_float(e1.y), acc1);
        acc2 = fmaf(v2, __int_as_float(e2.y), acc2);
        acc3 = fmaf(v3, __int_as_float(e3.y), acc3);
        acc0 = fmaf(v4, __int_as_float(e4.y), acc0);
        acc1 = fmaf(v5, __int_as_float(e5.y), acc1);
        acc2 = fmaf(v6, __int_as_float(e6.y), acc2);
        acc3 = fmaf(v7, __int_as_float(e7.y), acc3);
    }
    for (; k < k1; ++k) {
        int2 e = sw[k];
        acc0 = fmaf(h[(size_t)e.x * F_HID + j], __int_as_float(e.y), acc0);
    }
    h1[(size_t)node * F_HID + j] = fmaxf((acc0 + acc1) + (acc2 + acc3) + b1[j], 0.0f);
}

// ---------------- GEMM2: h1[N,64] @ W2[64,16] -> h2[N,16] ----------------
__global__ void k_gemm2(const float* __restrict__ h1, const float* __restrict__ W,
                        float* __restrict__ h2) {
    int t = blockIdx.x * blockDim.x + threadIdx.x;
    if (t < N_NODES * F_OUT) {
        int i = t >> 4, j = t & 15;
        float acc = 0.0f;
#pragma unroll
        for (int k = 0; k < F_HID; ++k)
            acc = fmaf(h1[(size_t)i * F_HID + k], W[k * F_OUT + j], acc);
        h2[t] = acc;
    }
}

// ---------------- CSR aggregation F=16: 4 groups x 16 feats, unroll-4 ---------
__global__ __launch_bounds__(256) void k_agg16_csr(const int* __restrict__ offs,
                                                   const int2* __restrict__ sw,
                                                   const float* __restrict__ dinv,
                                                   const float* __restrict__ h2,
                                                   const float* __restrict__ b2,
                                                   float* __restrict__ out) {
    int node = blockIdx.x * 4 + (threadIdx.x >> 6);
    int lane = threadIdx.x & 63;
    int eo = lane >> 4;
    int j  = lane & 15;
    if (node >= N_NODES) return;
    float dn = dinv[node];
    float acc0 = 0.0f, acc1 = 0.0f, acc2 = 0.0f, acc3 = 0.0f;
    int k0 = offs[node], k1 = offs[node + 1];
    int k = k0 + eo;
    for (; k + 12 < k1; k += 16) {
        int2 e0 = sw[k], e1 = sw[k + 4], e2 = sw[k + 8], e3 = sw[k + 12];
        float v0 = h2[(size_t)e0.x * F_OUT + j];
        float v1 = h2[(size_t)e1.x * F_OUT + j];
        float v2 = h2[(size_t)e2.x * F_OUT + j];
        float v3 = h2[(size_t)e3.x * F_OUT + j];
        acc0 = fmaf(v0, __int_as_float(e0.y), acc0);
        acc1 = fmaf(v1, __int_as_float(e1.y), acc1);
        acc2 = fmaf(v2, __int_as_float(e2.y), acc2);
        acc3 = fmaf(v3, __int_as_float(e3.y), acc3);
    }
    for (; k < k1; k += 4) {
        int2 e = sw[k];
        acc0 = fmaf(h2[(size_t)e.x * F_OUT + j], __int_as_float(e.y), acc0);
    }
    float acc = (acc0 + acc1) + (acc2 + acc3);
    acc += __shfl_xor(acc, 16);
    acc += __shfl_xor(acc, 32);
    if (eo == 0)
        out[(size_t)node * F_OUT + j] =
            acc + h2[(size_t)node * F_OUT + j] * dn * dn + b2[j];
}

extern "C" void kernel_launch(void* const* d_in, const int* in_sizes, int n_in,
                              void* d_out, int out_size, void* d_ws, size_t ws_size,
                              hipStream_t stream) {
    const float* x  = (const float*)d_in[0];
    const int*   ei = (const int*)d_in[1];
    const float* W1 = (const float*)d_in[2];
    const float* b1 = (const float*)d_in[3];
    const float* W2 = (const float*)d_in[4];
    const float* b2 = (const float*)d_in[5];
    float* out = (float*)d_out;

    const int* src = ei;
    const int* dst = ei + N_EDGES;

    int* wsi = (int*)d_ws;
    int* count      = wsi;                  // 50176 (consumed to 0 by k_fill)
    int* offs       = count + 50176;        // 50304
    int* bsum       = offs + 50304;         // 64
    int2* sw_sorted = (int2*)(bsum + 64);   // 800000 x 8B (8B-aligned: offset 100544*4)
    float* dinv = (float*)(sw_sorted + N_EDGES);         // 50176
    float* h    = dinv + 50176;                          // N*64
    float* h1   = h + (size_t)N_NODES * F_HID;           // N*64
    float* h2   = h;                                     // alias: h dead after agg64

    (void)hipMemsetAsync(count, 0, N_NODES * sizeof(int), stream);

    k_count<<<(N_EDGES + 255) / 256, 256, 0, stream>>>(dst, count);
    k_gemm1<<<(N_NODES + 63) / 64, 256, 0, stream>>>(x, W1, h);

    k_scanA<<<SCAN_NB, SCAN_B, 0, stream>>>(count, offs, bsum, dinv);
    k_scanBC<<<SCAN_NB, SCAN_B, 0, stream>>>(offs, bsum);
    k_fill<<<(N_EDGES + 255) / 256, 256, 0, stream>>>(src, dst, offs, count, dinv,
                                                      sw_sorted);

    k_agg64_csr<<<(N_NODES + 3) / 4, 256, 0, stream>>>(offs, sw_sorted, dinv, h, b1, h1);
    k_gemm2<<<(N_NODES * F_OUT + 255) / 256, 256, 0, stream>>>(h1, W2, h2);
    k_agg16_csr<<<(N_NODES + 3) / 4, 256, 0, stream>>>(offs, sw_sorted, dinv, h2, b2, out);
}